// Round 2
// baseline (291.935 us; speedup 1.0000x reference)
//
#include <hip/hip_runtime.h>
#include <hip/hip_bf16.h>

#define C   64
#define Hh  128
#define Ww  128
#define HW  16384

typedef __attribute__((ext_vector_type(8))) short bf16x8;
typedef __attribute__((ext_vector_type(4))) float f32x4;

__device__ __forceinline__ unsigned short f2bf(float f) {
    unsigned u = __builtin_bit_cast(unsigned, f);
    unsigned r = (u + 0x7fff + ((u >> 16) & 1)) >> 16;
    return (unsigned short)r;
}

// ---------------------------------------------------------------------------
// Prep: fold BN scale into 1x1 proj weights (bf16), compute shifts, and pack
// conv weights to wp[ch2][tap9][co64][ci32] bf16 for each conv half.
// ---------------------------------------------------------------------------
__global__ __launch_bounds__(256) void prep_kernel(
    const float* __restrict__ pu_w, const float* __restrict__ pu_g,
    const float* __restrict__ pu_b, const float* __restrict__ pu_m,
    const float* __restrict__ pu_v,
    const float* __restrict__ pv_w, const float* __restrict__ pv_g,
    const float* __restrict__ pv_b, const float* __restrict__ pv_m,
    const float* __restrict__ pv_v,
    const float* __restrict__ conv_w,
    short* __restrict__ pwu, short* __restrict__ pwv,
    short* __restrict__ wpu, short* __restrict__ wpv,
    float* __restrict__ shu, float* __restrict__ shv)
{
    const int idx = blockIdx.x * 256 + threadIdx.x;
    if (idx < 8192) {                       // proj weights, scale-folded
        const int c  = idx >> 12;
        const int r  = idx & 4095;
        const int co = r >> 6, ci = r & 63;
        const float* w = c ? pv_w : pu_w;
        const float* g = c ? pv_g : pu_g;
        const float* vv = c ? pv_v : pu_v;
        const float scale = g[co] * rsqrtf(vv[co] + 1e-5f);
        (c ? pwv : pwu)[r] = (short)f2bf(w[co * 64 + ci] * scale);
    } else if (idx < 81920) {               // conv weights repack
        const int flat = idx - 8192;
        const int c  = flat / 36864;
        const int r  = flat % 36864;
        const int ch  = r / 18432;
        const int r2  = r % 18432;
        const int tap = r2 / 2048;
        const int r3  = r2 & 2047;
        const int co = r3 >> 5, ci = r3 & 31;
        const float src = conv_w[(size_t)(co * 128 + c * 64 + ch * 32 + ci) * 9 + tap];
        (c ? wpv : wpu)[((ch * 9 + tap) * 64 + co) * 32 + ci] = (short)f2bf(src);
    } else if (idx < 82048) {               // shifts
        const int r  = idx - 81920;
        const int c  = r >> 6, co = r & 63;
        const float* g = c ? pv_g : pu_g;
        const float* b = c ? pv_b : pu_b;
        const float* m = c ? pv_m : pu_m;
        const float* vv = c ? pv_v : pu_v;
        const float scale = g[co] * rsqrtf(vv[co] + 1e-5f);
        (c ? shv : shu)[co] = b[co] - m[co] * scale;
    }
}

// ---------------------------------------------------------------------------
// Fused proj(1x1+BN+ReLU) + conv3x3, one block = 8h x 32w output tile.
// Phase 1: transpose-stage input halo 10x34 cells as [cell][ci64] bf16 in LDS.
// Phase 2: proj MFMA (M=cells padded to 384, N=co64, K=64), relu+shift,
//          write back IN PLACE as [cell][co] bf16. OOB halo cells forced to 0
//          (reference zero-pads the post-ReLU activation).
// Phase 3: conv implicit-GEMM, weights staged per ky-row (3 taps = 15.4 KB).
// FUSED=false: write ou[img][co][hw] fp32 (stays L3-resident).
// FUSED=true : cross-add epilogue: out[b][sx][sy] = ou[b4+sx] + acc + bias.
// LDS: 52.2 + 15.4 + 8 + 0.5 KB = 76.3 KB -> 2 blocks/CU.
// ---------------------------------------------------------------------------
template<bool FUSED>
__global__ __launch_bounds__(256, 2) void fused_pc(
    const float* __restrict__ xg, const short* __restrict__ pw,
    const float* __restrict__ shg, const short* __restrict__ wp,
    const float* __restrict__ oug, const float* __restrict__ bias,
    float* __restrict__ outp)
{
    __shared__ short xs2[384 * 68];       // [cell][64 + 4 pad]  52,224 B
    __shared__ short wsm[3 * 64 * 40];    // [tap3][co][32 + 8]  15,360 B
    __shared__ short pwl[64 * 64];        // [co][64] XOR-swizzled 8,192 B
    __shared__ float ssh[64];
    __shared__ float sbias[64];

    const int img = blockIdx.y;
    const int tx = blockIdx.x & 3, ty = blockIdx.x >> 2;
    const int h0 = ty * 8, w0 = tx * 32;
    const int tid = threadIdx.x;
    const int wq = tid >> 6;
    const int lane = tid & 63;
    const int lx = lane & 15;
    const int q  = lane >> 4;

    // ---- phase 1: stage proj weights (swizzled), shift/bias, conv wgt ky=0,
    //      and transpose input halo fp32 -> bf16 [cell][ci] ----
#pragma unroll
    for (int it = 0; it < 2; ++it) {
        const int idx = tid + it * 256;          // 512 16B chunks
        const int oct = idx & 7, co = idx >> 3;
        *(int4*)&pwl[co * 64 + ((oct * 8) ^ ((co & 7) << 3))] =
            *(const int4*)&pw[co * 64 + oct * 8];
    }
    if (tid < 64) ssh[tid] = shg[tid];
    if (FUSED && tid >= 64 && tid < 128) sbias[tid - 64] = bias[tid - 64];
#pragma unroll
    for (int it = 0; it < 3; ++it) {             // conv weights ch0, ky0
        const int idx = tid + it * 256;
        const int oct = idx & 3, co = (idx >> 2) & 63, tl = idx >> 8;
        *(int4*)&wsm[(tl * 64 + co) * 40 + oct * 8] =
            *(const int4*)&wp[(tl * 64 + co) * 32 + oct * 8];
    }
    const float* xb = xg + (size_t)img * C * HW;
    for (int idx = tid; idx < 10880; idx += 256) {   // 32 ci-pairs x 340 cells
        const int p = idx / 340;
        const int cell = idx - p * 340;
        const int h = cell / 34, w2 = cell - h * 34;
        const int gh = h0 - 1 + h, gw = w0 - 1 + w2;
        int packed = 0;
        if (gh >= 0 && gh < Hh && gw >= 0 && gw < Ww) {
            const float* s = xb + (size_t)(2 * p) * HW + gh * Ww + gw;
            packed = (int)f2bf(s[0]) | ((int)f2bf(s[HW]) << 16);
        }
        *(int*)&xs2[cell * 68 + p * 2] = packed;
    }
    __syncthreads();

    // ---- phase 2: proj MFMA, 6 m-tiles/wave (24 tiles = 384 px >= 340) ----
    f32x4 pacc[6][4];
#pragma unroll
    for (int mt = 0; mt < 6; ++mt)
#pragma unroll
        for (int nt = 0; nt < 4; ++nt) pacc[mt][nt] = (f32x4){0.f, 0.f, 0.f, 0.f};

#pragma unroll
    for (int kc = 0; kc < 2; ++kc) {
        bf16x8 pa[6], pb[4];
#pragma unroll
        for (int mt = 0; mt < 6; ++mt)
            pa[mt] = *(const bf16x8*)&xs2[((wq * 6 + mt) * 16 + lx) * 68 + kc * 32 + q * 8];
#pragma unroll
        for (int nt = 0; nt < 4; ++nt) {
            const int row = nt * 16 + lx;
            const int off = kc * 32 + q * 8;
            pb[nt] = *(const bf16x8*)&pwl[row * 64 + (off ^ ((row & 7) << 3))];
        }
#pragma unroll
        for (int mt = 0; mt < 6; ++mt)
#pragma unroll
            for (int nt = 0; nt < 4; ++nt)
                pacc[mt][nt] = __builtin_amdgcn_mfma_f32_16x16x32_bf16(pa[mt], pb[nt], pacc[mt][nt], 0, 0, 0);
    }
    __syncthreads();
    // write back in place: [cell][co] bf16 with relu+shift, OOB cells -> 0
#pragma unroll
    for (int mt = 0; mt < 6; ++mt)
#pragma unroll
        for (int r = 0; r < 4; ++r) {
            const int px = (wq * 6 + mt) * 16 + q * 4 + r;
            const int h = px / 34, w2 = px - h * 34;
            const int gh = h0 - 1 + h, gw = w0 - 1 + w2;
            const bool ok = (gh >= 0) && (gh < Hh) && (gw >= 0) && (gw < Ww) && (px < 340);
#pragma unroll
            for (int nt = 0; nt < 4; ++nt) {
                const int co = nt * 16 + lx;
                const float vv = ok ? fmaxf(pacc[mt][nt][r] + ssh[co], 0.f) : 0.f;
                xs2[px * 68 + co] = (short)f2bf(vv);
            }
        }
    __syncthreads();

    // ---- phase 3: conv 3x3, ky-row weight groups ----
    f32x4 acc[4][4];
#pragma unroll
    for (int mt = 0; mt < 4; ++mt)
#pragma unroll
        for (int nt = 0; nt < 4; ++nt) acc[mt][nt] = (f32x4){0.f, 0.f, 0.f, 0.f};

    for (int ch = 0; ch < 2; ++ch) {
        for (int g = 0; g < 3; ++g) {            // g == ky
            if (ch | g) {
                __syncthreads();                 // prior group's reads done
                for (int idx = tid; idx < 768; idx += 256) {
                    const int oct = idx & 3, co = (idx >> 2) & 63, tl = idx >> 8;
                    *(int4*)&wsm[(tl * 64 + co) * 40 + oct * 8] =
                        *(const int4*)&wp[((ch * 9 + g * 3 + tl) * 64 + co) * 32 + oct * 8];
                }
                __syncthreads();
            }
#pragma unroll
            for (int tl = 0; tl < 3; ++tl) {     // tl == kx
                bf16x8 a[4], b[4];
#pragma unroll
                for (int mt = 0; mt < 4; ++mt)
                    a[mt] = *(const bf16x8*)&wsm[(tl * 64 + mt * 16 + lx) * 40 + q * 8];
#pragma unroll
                for (int nt = 0; nt < 4; ++nt) {
                    const int cell = (2 * wq + (nt >> 1) + g) * 34 + (nt & 1) * 16 + lx + tl;
                    b[nt] = *(const bf16x8*)&xs2[cell * 68 + ch * 32 + q * 8];
                }
#pragma unroll
                for (int mt = 0; mt < 4; ++mt)
#pragma unroll
                    for (int nt = 0; nt < 4; ++nt)
                        acc[mt][nt] = __builtin_amdgcn_mfma_f32_16x16x32_bf16(a[mt], b[nt], acc[mt][nt], 0, 0, 0);
            }
        }
    }

    // ---- epilogue ----
    const int qq = lane >> 4;
    if (!FUSED) {
        float* ob = outp + (size_t)img * C * HW;
#pragma unroll
        for (int mt = 0; mt < 4; ++mt)
#pragma unroll
            for (int nt = 0; nt < 4; ++nt)
#pragma unroll
                for (int r = 0; r < 4; ++r) {
                    const int co = mt * 16 + qq * 4 + r;
                    const int h = h0 + 2 * wq + (nt >> 1);
                    const int w = w0 + (nt & 1) * 16 + lx;
                    ob[(size_t)co * HW + h * Ww + w] = acc[mt][nt][r];
                }
    } else {
        const int b  = img >> 2;
        const int sy = img & 3;
#pragma unroll
        for (int mt = 0; mt < 4; ++mt)
#pragma unroll
            for (int nt = 0; nt < 4; ++nt)
#pragma unroll
                for (int r = 0; r < 4; ++r)
                    acc[mt][nt][r] += sbias[mt * 16 + qq * 4 + r];

#pragma unroll
        for (int sx = 0; sx < 4; ++sx) {
            const float* oub = oug + (size_t)(b * 4 + sx) * C * HW;
            float* ob = outp + ((size_t)((b * 4 + sx) * 4 + sy)) * C * HW;
#pragma unroll
            for (int mt = 0; mt < 4; ++mt)
#pragma unroll
                for (int nt = 0; nt < 4; ++nt)
#pragma unroll
                    for (int r = 0; r < 4; ++r) {
                        const int co = mt * 16 + qq * 4 + r;
                        const int h = h0 + 2 * wq + (nt >> 1);
                        const int w = w0 + (nt & 1) * 16 + lx;
                        const size_t off = (size_t)co * HW + h * Ww + w;
                        __builtin_nontemporal_store(acc[mt][nt][r] + oub[off], &ob[off]);
                    }
        }
    }
}

// ---------------------------------------------------------------------------
extern "C" void kernel_launch(void* const* d_in, const int* in_sizes, int n_in,
                              void* d_out, int out_size, void* d_ws, size_t ws_size,
                              hipStream_t stream)
{
    const float* u        = (const float*)d_in[0];
    const float* v        = (const float*)d_in[1];
    const float* pu_w     = (const float*)d_in[2];
    const float* pu_gamma = (const float*)d_in[3];
    const float* pu_beta  = (const float*)d_in[4];
    const float* pu_mean  = (const float*)d_in[5];
    const float* pu_var   = (const float*)d_in[6];
    const float* pv_w     = (const float*)d_in[7];
    const float* pv_gamma = (const float*)d_in[8];
    const float* pv_beta  = (const float*)d_in[9];
    const float* pv_mean  = (const float*)d_in[10];
    const float* pv_var   = (const float*)d_in[11];
    const float* conv_w   = (const float*)d_in[12];
    const float* conv_b   = (const float*)d_in[13];
    float* out = (float*)d_out;

    char* ws = (char*)d_ws;
    float* ou  = (float*)(ws);                         // 33,554,432 B
    char*  aux = ws + 33554432;
    short* pwu = (short*)(aux);                        // 8192 B
    short* pwv = (short*)(aux + 8192);                 // 8192 B
    short* wpu = (short*)(aux + 16384);                // 73,728 B
    short* wpv = (short*)(aux + 90112);                // 73,728 B
    float* shu = (float*)(aux + 163840);               // 256 B
    float* shv = (float*)(aux + 164096);               // 256 B

    prep_kernel<<<321, 256, 0, stream>>>(pu_w, pu_gamma, pu_beta, pu_mean, pu_var,
                                         pv_w, pv_gamma, pv_beta, pv_mean, pv_var,
                                         conv_w, pwu, pwv, wpu, wpv, shu, shv);

    dim3 gc(64, 8);
    fused_pc<false><<<gc, 256, 0, stream>>>(u, pwu, shu, wpu, nullptr, nullptr, ou);
    fused_pc<true ><<<gc, 256, 0, stream>>>(v, pwv, shv, wpv, ou, conv_b, out);
}

// Round 4
// 263.556 us; speedup vs baseline: 1.1077x; 1.1077x over previous
//
#include <hip/hip_runtime.h>
#include <hip/hip_bf16.h>

#define C   64
#define Hh  128
#define Ww  128
#define HW  16384

typedef __attribute__((ext_vector_type(8))) short bf16x8;
typedef __attribute__((ext_vector_type(4))) float f32x4;

__device__ __forceinline__ unsigned short f2bf(float f) {
    unsigned u = __builtin_bit_cast(unsigned, f);
    unsigned r = (u + 0x7fff + ((u >> 16) & 1)) >> 16;
    return (unsigned short)r;
}

// ---------------------------------------------------------------------------
// Prep: fold BN scale into 1x1 proj weights (bf16), compute shifts, and pack
// conv weights to wp[ch2][tap9][co64][ci32] bf16 for each conv half.
// ---------------------------------------------------------------------------
__global__ __launch_bounds__(256) void prep_kernel(
    const float* __restrict__ pu_w, const float* __restrict__ pu_g,
    const float* __restrict__ pu_b, const float* __restrict__ pu_m,
    const float* __restrict__ pu_v,
    const float* __restrict__ pv_w, const float* __restrict__ pv_g,
    const float* __restrict__ pv_b, const float* __restrict__ pv_m,
    const float* __restrict__ pv_v,
    const float* __restrict__ conv_w,
    short* __restrict__ pwu, short* __restrict__ pwv,
    short* __restrict__ wpu, short* __restrict__ wpv,
    float* __restrict__ shu, float* __restrict__ shv)
{
    const int idx = blockIdx.x * 256 + threadIdx.x;
    if (idx < 8192) {                       // proj weights, scale-folded
        const int c  = idx >> 12;
        const int r  = idx & 4095;
        const int co = r >> 6, ci = r & 63;
        const float* w = c ? pv_w : pu_w;
        const float* g = c ? pv_g : pu_g;
        const float* vv = c ? pv_v : pu_v;
        const float scale = g[co] * rsqrtf(vv[co] + 1e-5f);
        (c ? pwv : pwu)[r] = (short)f2bf(w[co * 64 + ci] * scale);
    } else if (idx < 81920) {               // conv weights repack
        const int flat = idx - 8192;
        const int c  = flat / 36864;
        const int r  = flat % 36864;
        const int ch  = r / 18432;
        const int r2  = r % 18432;
        const int tap = r2 / 2048;
        const int r3  = r2 & 2047;
        const int co = r3 >> 5, ci = r3 & 31;
        const float src = conv_w[(size_t)(co * 128 + c * 64 + ch * 32 + ci) * 9 + tap];
        (c ? wpv : wpu)[((ch * 9 + tap) * 64 + co) * 32 + ci] = (short)f2bf(src);
    } else if (idx < 82048) {               // shifts
        const int r  = idx - 81920;
        const int c  = r >> 6, co = r & 63;
        const float* g = c ? pv_g : pu_g;
        const float* b = c ? pv_b : pu_b;
        const float* m = c ? pv_m : pu_m;
        const float* vv = c ? pv_v : pu_v;
        const float scale = g[co] * rsqrtf(vv[co] + 1e-5f);
        (c ? shv : shu)[co] = b[co] - m[co] * scale;
    }
}

// ---------------------------------------------------------------------------
// Proj: y[img][pix][co] = bf16(relu( sum_ci x[img][ci][pix]*pw[co][ci] + sh ))
// MFMA 16x16x32, M=pix(256), N=co(64), K=64. One launch for u(y<8) + v(>=8).
// Epilogue writes bf16 back into xs then copies out 16 B/lane coalesced.
// ---------------------------------------------------------------------------
__global__ __launch_bounds__(256, 3) void proj_mfma(
    const float* __restrict__ xu, const float* __restrict__ xv,
    const short* __restrict__ pwu_, const short* __restrict__ pwv_,
    const float* __restrict__ shu_, const float* __restrict__ shv_,
    short* __restrict__ yu, short* __restrict__ yv)
{
    __shared__ short xs[256 * 72];      // [pix][64ci + 8 pad] bf16 36,864 B
    __shared__ short pwl[64 * 72];      // [co][64ci + 8 pad]         9,216 B
    __shared__ float ssh[64];

    const int img16 = blockIdx.y;
    const int sel   = img16 >> 3;
    const int img   = img16 & 7;
    const float* x      = sel ? xv   : xu;
    const short* pw     = sel ? pwv_ : pwu_;
    const float* shiftg = sel ? shv_ : shu_;
    short* y            = sel ? yv   : yu;

    const int pix0 = blockIdx.x * 256;
    const int tid  = threadIdx.x;

    // ---- stage x: transpose [ci][pix] fp32 -> [pix][ci] bf16 ----
    const float* xi = x + (size_t)img * C * HW + pix0 + tid;
#pragma unroll 8
    for (int c2 = 0; c2 < 32; ++c2) {
        const float a = xi[(size_t)(2 * c2) * HW];
        const float b = xi[(size_t)(2 * c2 + 1) * HW];
        const int packed = (int)f2bf(a) | ((int)f2bf(b) << 16);
        *(int*)(&xs[tid * 72 + c2 * 2]) = packed;
    }
    // ---- stage weights (16B chunks) + shift ----
#pragma unroll
    for (int it = 0; it < 2; ++it) {
        const int idx = tid + it * 256;      // 512 chunks
        const int oct = idx & 7, co = idx >> 3;
        *(int4*)(&pwl[co * 72 + oct * 8]) = *(const int4*)(&pw[co * 64 + oct * 8]);
    }
    if (tid < 64) ssh[tid] = shiftg[tid];
    __syncthreads();

    const int wq = tid >> 6;
    const int lane = tid & 63;
    const int lx = lane & 15;
    const int q  = lane >> 4;

    f32x4 acc[4][4];
#pragma unroll
    for (int mt = 0; mt < 4; ++mt)
#pragma unroll
        for (int nt = 0; nt < 4; ++nt) acc[mt][nt] = (f32x4){0.f, 0.f, 0.f, 0.f};

#pragma unroll
    for (int kc = 0; kc < 2; ++kc) {
        bf16x8 a[4], b[4];
#pragma unroll
        for (int mt = 0; mt < 4; ++mt)
            a[mt] = *(const bf16x8*)&xs[((wq * 4 + mt) * 16 + lx) * 72 + kc * 32 + q * 8];
#pragma unroll
        for (int nt = 0; nt < 4; ++nt)
            b[nt] = *(const bf16x8*)&pwl[(nt * 16 + lx) * 72 + kc * 32 + q * 8];
#pragma unroll
        for (int mt = 0; mt < 4; ++mt)
#pragma unroll
            for (int nt = 0; nt < 4; ++nt)
                acc[mt][nt] = __builtin_amdgcn_mfma_f32_16x16x32_bf16(a[mt], b[nt], acc[mt][nt], 0, 0, 0);
    }

    // ---- epilogue: relu+shift -> bf16 back into xs as [pix][co], then
    //      coalesced int4 copy-out ----
    __syncthreads();      // all LDS reads for MFMA done
#pragma unroll
    for (int mt = 0; mt < 4; ++mt)
#pragma unroll
        for (int nt = 0; nt < 4; ++nt)
#pragma unroll
            for (int r = 0; r < 4; ++r) {
                const int px = (wq * 4 + mt) * 16 + q * 4 + r;
                const int co = nt * 16 + lx;
                float vv = acc[mt][nt][r] + ssh[co];
                vv = fmaxf(vv, 0.f);
                xs[px * 72 + co] = (short)f2bf(vv);
            }
    __syncthreads();
    short* yo = y + ((size_t)img * HW + pix0) * C;
#pragma unroll
    for (int it = 0; it < 8; ++it) {
        const int idx = tid + it * 256;      // 2048 int4 chunks
        const int oct = idx & 7, px = idx >> 3;
        *(int4*)&yo[(size_t)px * C + oct * 8] = *(const int4*)&xs[px * 72 + oct * 8];
    }
}

// ---------------------------------------------------------------------------
// Conv 3x3 pad=1, implicit GEMM MFMA 16x16x32. Tile 4h x 32w (1024 blocks).
// M=co(64), N=128 px; wave wq owns h-row wq (2 nt tiles of 16 w).
// Activations (both ci-halves) staged ONCE: [6h x 34w][64+4pad] = 27.7 KB,
// single barrier. Weight A-fragments read directly from L2 (wp is 73 KB,
// L2-resident; 16 B/lane coalesced) -> straight 144-MFMA run per wave.
// Epilogue transposes each 16co x 128px acc slab through LDS so all HBM
// reads/writes are full-line coalesced float4.
// FUSED=false: write ou[img][co][hw] fp32 (stays LLC-resident).
// FUSED=true : out[b][sx][sy] = acc + bias + ou[b*4+sx], nontemporal.
// LDS 36.5 KB -> 4 blocks/CU (16 waves/CU).
// ---------------------------------------------------------------------------
template<bool FUSED>
__global__ __launch_bounds__(256, 4) void conv_fused(
    const short* __restrict__ act, const short* __restrict__ wp,
    const float* __restrict__ oug, const float* __restrict__ bias,
    float* __restrict__ outp)
{
    __shared__ short xs[204 * 68];     // 27,744 B halo [cell][ci]
    __shared__ float ts[16 * 132];     //  8,448 B transpose slab
    __shared__ float sbias[64];

    const int img = blockIdx.y;
    const int tx = blockIdx.x & 3, ty = blockIdx.x >> 2;
    const int h0 = ty * 4, w0 = tx * 32;
    const int tid = threadIdx.x;
    const int wq = tid >> 6;
    const int lane = tid & 63;
    const int lx = lane & 15;
    const int q  = lane >> 4;
    const int q8 = q * 8;

    if (FUSED && tid < 64) sbias[tid] = bias[tid];

    // ---- stage halo (both ci halves), zero OOB ----
    const short* ub = act + (size_t)img * HW * C;
    for (int idx = tid; idx < 1632; idx += 256) {   // 204 cells x 8 octs
        const int oct = idx & 7;
        const int cell = idx >> 3;
        const int h = cell / 34, w = cell - h * 34;
        const int gh = h0 - 1 + h, gw = w0 - 1 + w;
        int4 v = {0, 0, 0, 0};
        if (gh >= 0 && gh < Hh && gw >= 0 && gw < Ww)
            v = *(const int4*)&ub[(size_t)(gh * Ww + gw) * C + oct * 8];
        *(int4*)(&xs[cell * 68 + oct * 8]) = v;
    }
    __syncthreads();

    f32x4 acc[4][2];
#pragma unroll
    for (int mt = 0; mt < 4; ++mt)
#pragma unroll
        for (int nt = 0; nt < 2; ++nt) acc[mt][nt] = (f32x4){0.f, 0.f, 0.f, 0.f};

    // ---- 144 MFMAs, weights direct from L2, no barriers ----
#pragma unroll
    for (int ch = 0; ch < 2; ++ch)
#pragma unroll
        for (int t = 0; t < 9; ++t) {
            const int ky = t / 3;
            const int kx = t - ky * 3;
            bf16x8 a[4], b[2];
#pragma unroll
            for (int mt = 0; mt < 4; ++mt)
                a[mt] = *(const bf16x8*)&wp[(((ch * 9 + t) * 64) + mt * 16 + lx) * 32 + q8];
#pragma unroll
            for (int nt = 0; nt < 2; ++nt) {
                const int cell = (wq + ky) * 34 + nt * 16 + lx + kx;
                b[nt] = *(const bf16x8*)&xs[cell * 68 + ch * 32 + q8];
            }
#pragma unroll
            for (int mt = 0; mt < 4; ++mt)
#pragma unroll
                for (int nt = 0; nt < 2; ++nt)
                    acc[mt][nt] = __builtin_amdgcn_mfma_f32_16x16x32_bf16(a[mt], b[nt], acc[mt][nt], 0, 0, 0);
        }

    // ---- epilogue: per-mt LDS transpose -> full-line coalesced I/O ----
    if (FUSED) {
#pragma unroll
        for (int mt = 0; mt < 4; ++mt)
#pragma unroll
            for (int nt = 0; nt < 2; ++nt)
#pragma unroll
                for (int r = 0; r < 4; ++r)
                    acc[mt][nt][r] += sbias[mt * 16 + q * 4 + r];
    }

    const int b  = img >> 2;
    const int sy = img & 3;

#pragma unroll
    for (int mt = 0; mt < 4; ++mt) {
        __syncthreads();
#pragma unroll
        for (int nt = 0; nt < 2; ++nt)
#pragma unroll
            for (int r = 0; r < 4; ++r)
                ts[(q * 4 + r) * 132 + wq * 32 + nt * 16 + lx] = acc[mt][nt][r];
        __syncthreads();
        if (!FUSED) {
            float* ob = outp + (size_t)img * C * HW;
#pragma unroll
            for (int k = 0; k < 2; ++k) {
                const int f = tid + k * 256;        // 512 float4 chunks
                const int co = f >> 5, c2 = f & 31;
                const int px = c2 * 4;
                const int h2 = px >> 5, w2 = px & 31;
                *(f32x4*)&ob[(size_t)(mt * 16 + co) * HW + (h0 + h2) * Ww + w0 + w2] =
                    *(const f32x4*)&ts[co * 132 + c2 * 4];
            }
        } else {
#pragma unroll
            for (int k = 0; k < 2; ++k) {
                const int f = tid + k * 256;
                const int co = f >> 5, c2 = f & 31;
                const int px = c2 * 4;
                const int h2 = px >> 5, w2 = px & 31;
                const size_t off = (size_t)(mt * 16 + co) * HW + (h0 + h2) * Ww + w0 + w2;
                const f32x4 tv = *(const f32x4*)&ts[co * 132 + c2 * 4];
#pragma unroll
                for (int sx = 0; sx < 4; ++sx) {
                    const f32x4 o = *(const f32x4*)&oug[(size_t)(b * 4 + sx) * C * HW + off];
                    f32x4 rr = tv + o;
                    __builtin_nontemporal_store(rr,
                        (f32x4*)&outp[((size_t)((b * 4 + sx) * 4 + sy)) * C * HW + off]);
                }
            }
        }
    }
}

// ---------------------------------------------------------------------------
extern "C" void kernel_launch(void* const* d_in, const int* in_sizes, int n_in,
                              void* d_out, int out_size, void* d_ws, size_t ws_size,
                              hipStream_t stream)
{
    const float* u        = (const float*)d_in[0];
    const float* v        = (const float*)d_in[1];
    const float* pu_w     = (const float*)d_in[2];
    const float* pu_gamma = (const float*)d_in[3];
    const float* pu_beta  = (const float*)d_in[4];
    const float* pu_mean  = (const float*)d_in[5];
    const float* pu_var   = (const float*)d_in[6];
    const float* pv_w     = (const float*)d_in[7];
    const float* pv_gamma = (const float*)d_in[8];
    const float* pv_beta  = (const float*)d_in[9];
    const float* pv_mean  = (const float*)d_in[10];
    const float* pv_var   = (const float*)d_in[11];
    const float* conv_w   = (const float*)d_in[12];
    const float* conv_b   = (const float*)d_in[13];
    float* out = (float*)d_out;

    char* ws = (char*)d_ws;
    short* uf  = (short*)(ws);                         // 16,777,216 B
    short* vf  = (short*)(ws + 16777216);              // 16,777,216 B
    float* ou  = (float*)(ws + 33554432);              // 33,554,432 B
    char*  aux = ws + 67108864;
    short* pwu = (short*)(aux);                        // 8192 B
    short* pwv = (short*)(aux + 8192);                 // 8192 B
    short* wpu = (short*)(aux + 16384);                // 73,728 B
    short* wpv = (short*)(aux + 90112);                // 73,728 B
    float* shu = (float*)(aux + 163840);               // 256 B
    float* shv = (float*)(aux + 164096);               // 256 B

    prep_kernel<<<321, 256, 0, stream>>>(pu_w, pu_gamma, pu_beta, pu_mean, pu_var,
                                         pv_w, pv_gamma, pv_beta, pv_mean, pv_var,
                                         conv_w, pwu, pwv, wpu, wpv, shu, shv);

    dim3 gp(64, 16);
    proj_mfma<<<gp, 256, 0, stream>>>(u, v, pwu, pwv, shu, shv, uf, vf);

    dim3 gc(128, 8);
    conv_fused<false><<<gc, 256, 0, stream>>>(uf, wpu, nullptr, nullptr, ou);
    conv_fused<true ><<<gc, 256, 0, stream>>>(vf, wpv, ou, conv_b, out);
}